// Round 10
// baseline (182.572 us; speedup 1.0000x reference)
//
#include <hip/hip_runtime.h>
#include <hip/hip_bf16.h>

typedef __attribute__((ext_vector_type(8)))  short bf16x8;
typedef __attribute__((ext_vector_type(16))) float f32x16;

#define TPB 512
// MFMA score error bound ~1e-4 (bf16 hi/lo split of ya, fp32 accumulate, C-add);
// 1e-3 margin gives ~10x headroom -> unflagged decisions provably match fp64.
#define SCORE_MARGIN 1e-3f
#define ERR_MARGIN   1e-3f

static __device__ __forceinline__ unsigned short bf16_rne(float v) {
    union { __hip_bfloat16 h; unsigned short u; } cv;
    cv.h = __float2bfloat16(v);
    return cv.u;
}

// ---------------------------------------------------------------------------
// Single fused kernel, mfma_f32_32x32x16_bf16 (verified since R8, absmax 0.0):
// A = codewords (32 cw/tile, K = 8 dims x {hi,lo}; 1 broadcast ds_read_b128),
// B = ya (loop-invariant hi/lo), C = -n/2 (bf16-packed, permuted to C-reg
// order). R10: (1) C built IN-PLACE into the MFMA destination block
// (acc = mfma(a,b,acc)) to kill compiler register copies around the MFMA;
// (2) explicit 1-tile prefetch of afrag + norm words (hide LDS latency at
// ~2 waves/SIMD); (3) 512 blocks x 2 jobs/wave (all blocks resident, staging
// amortized). Margin flags + inline wave-cooperative fp64 fixup unchanged.
// Output d_out (float32): [final_vals (N*8) | final_idxs (N)].
// ---------------------------------------------------------------------------
__global__ __launch_bounds__(TPB, 4) void e8p_fused(
    const float* __restrict__ X,
    const float* __restrict__ grid_part,
    const float* __restrict__ grid_part_norm,
    const int*   __restrict__ allcombo_idx,
    const int*   __restrict__ idx_map,
    float* __restrict__ out,
    int N, int G, int T, int nJobs, int jobStride)
{
    extern __shared__ __align__(16) unsigned char smem[];
    const int T32 = T * 32;
    unsigned char* ldsG = smem;                       // T32 cw x 16B bf16x8
    unsigned short* ldsN = (unsigned short*)(smem + (size_t)T32 * 16);
    // ldsN: per tile 32 bf16 = [h=0: 16 slots r][h=1: 16 slots r], value -n/2

    const int tid = threadIdx.x;

    // ---- stage codebook: g as bf16x8 (exact); -n/2 bf16 permuted to C order
    for (int c = tid; c < T32; c += TPB) {
        uint4 gv; float nv;
        if (c < G) {
            const float4 g0 = *(const float4*)(grid_part + (size_t)c * 8);
            const float4 g1 = *(const float4*)(grid_part + (size_t)c * 8 + 4);
            gv.x = (unsigned)bf16_rne(g0.x) | ((unsigned)bf16_rne(g0.y) << 16);
            gv.y = (unsigned)bf16_rne(g0.z) | ((unsigned)bf16_rne(g0.w) << 16);
            gv.z = (unsigned)bf16_rne(g1.x) | ((unsigned)bf16_rne(g1.y) << 16);
            gv.w = (unsigned)bf16_rne(g1.z) | ((unsigned)bf16_rne(g1.w) << 16);
            nv = -0.5f * grid_part_norm[c];           // in {-1..-6}: bf16-exact
        } else {
            gv.x = gv.y = gv.z = gv.w = 0u;  // pad cw: dot 0, C-slot -30000
            nv = -30000.0f;                  // (bf16 ~ -29952, never wins/sec)
        }
        *(uint4*)(ldsG + (size_t)c * 16) = gv;
        // C/D row w = (r&3) + 8*(r>>2) + 4h  ->  h = (w>>2)&1, r = (w&3)+4*(w>>3)
        const int t = c >> 5, w = c & 31;
        const int h = (w >> 2) & 1;
        const int r = (w & 3) + 4 * (w >> 3);
        ldsN[t * 32 + h * 16 + r] = bf16_rne(nv);
    }
    __syncthreads();

    const int lane = tid & 63;
    const int h    = lane >> 5;        // k-half / C-row offset 4h
    const int col  = lane & 31;        // B col = (input row, branch)
    const int wave0 = blockIdx.x * (TPB / 64) + (tid >> 6);

    const int li     = col >> 1;
    const int branch = col & 1;        // 0: +0.25, 1: -0.25
    const unsigned aoff = (unsigned)col * 16u;
    const unsigned char* nbase = (const unsigned char*)ldsN + h * 32;

    for (int job = wave0; job < nJobs; job += jobStride) {
        const int irow  = job * 16 + li;
        const int iload = (irow < N) ? irow : 0;

        float x[8];
        {
            const float4 a = *(const float4*)(X + (size_t)iload * 8);
            const float4 b = *(const float4*)(X + (size_t)iload * 8 + 4);
            x[0]=a.x; x[1]=a.y; x[2]=a.z; x[3]=a.w;
            x[4]=b.x; x[5]=b.y; x[6]=b.z; x[7]=b.w;
        }

        // Branch prep (fp32 signs == fp64 signs)
        float ya[8]; int neg = 0;
        const float sh = branch ? -0.25f : 0.25f;
#pragma unroll
        for (int j = 0; j < 8; ++j) {
            const float yj = x[j] + sh;
            if (yj < 0.0f) neg |= (1 << (7 - j));
            ya[j] = fabsf(yj);
        }
        int mint = neg;
        if (__popc(neg) & 1) { ya[0] = -ya[0]; mint ^= 128; }

        // B fragment: h=0 -> bf16_hi(ya), h=1 -> bf16_lo residual
        bf16x8 bfrag;
#pragma unroll
        for (int j = 0; j < 8; ++j) {
            const unsigned short hi = bf16_rne(ya[j]);
            const unsigned short lo = bf16_rne(ya[j] - __uint_as_float(((unsigned)hi) << 16));
            bfrag[j] = (short)(h ? lo : hi);
        }

        float best[16], sec[16]; int q[16];
#pragma unroll
        for (int r = 0; r < 16; ++r) { best[r] = -1e30f; sec[r] = -1e30f; q[r] = 0; }

        // 1-tile prefetch
        bf16x8 afragN = *(const bf16x8*)(ldsG + aoff);
        uint4 n0N = *(const uint4*)(nbase);
        uint4 n1N = *(const uint4*)(nbase + 16);

        for (int t = 0; t < T; ++t) {
            const bf16x8 afrag = afragN;
            const uint4 n0 = n0N, n1 = n1N;
            const int tn = (t + 1 < T) ? (t + 1) : t;
            afragN = *(const bf16x8*)(ldsG + (size_t)tn * 512 + aoff);
            n0N = *(const uint4*)(nbase + (size_t)tn * 64);
            n1N = *(const uint4*)(nbase + (size_t)tn * 64 + 16);

            // Build C directly in the MFMA destination block (C==D in-place).
            f32x16 acc;
            acc[0]  = __uint_as_float(n0.x << 16);
            acc[1]  = __uint_as_float(n0.x & 0xffff0000u);
            acc[2]  = __uint_as_float(n0.y << 16);
            acc[3]  = __uint_as_float(n0.y & 0xffff0000u);
            acc[4]  = __uint_as_float(n0.z << 16);
            acc[5]  = __uint_as_float(n0.z & 0xffff0000u);
            acc[6]  = __uint_as_float(n0.w << 16);
            acc[7]  = __uint_as_float(n0.w & 0xffff0000u);
            acc[8]  = __uint_as_float(n1.x << 16);
            acc[9]  = __uint_as_float(n1.x & 0xffff0000u);
            acc[10] = __uint_as_float(n1.y << 16);
            acc[11] = __uint_as_float(n1.y & 0xffff0000u);
            acc[12] = __uint_as_float(n1.z << 16);
            acc[13] = __uint_as_float(n1.z & 0xffff0000u);
            acc[14] = __uint_as_float(n1.w << 16);
            acc[15] = __uint_as_float(n1.w & 0xffff0000u);
            acc = __builtin_amdgcn_mfma_f32_32x32x16_bf16(afrag, bfrag, acc, 0, 0, 0);
#pragma unroll
            for (int r = 0; r < 16; ++r) {
                const float s = acc[r];
                const bool gt = s > best[r];          // first-max-wins per slot
                sec[r]  = __builtin_amdgcn_fmed3f(s, best[r], sec[r]);
                best[r] = fmaxf(best[r], s);
                q[r]    = gt ? t : q[r];
            }
        }

        // ---- reduce 16 slots -> 1 (lexicographic max-score, min-index)
        float bb = best[0], ss = sec[0];
        int   ii = 32 * q[0] + 4 * h;                 // r=0 rowoff = 4h
#pragma unroll
        for (int r = 1; r < 16; ++r) {
            const int rowoff = (r & 3) + 8 * (r >> 2) + 4 * h;
            const int idx = 32 * q[r] + rowoff;
            const float br = best[r];
            ss = fmaxf(fmaxf(ss, sec[r]), fminf(bb, br));
            const bool take = (br > bb) || ((br == bb) && (idx < ii));
            bb = fmaxf(bb, br);
            ii = take ? idx : ii;
        }
        {   // butterfly across the two k-half lane groups (offset 32)
            const float ob = __shfl_xor(bb, 32, 64);
            const float os = __shfl_xor(ss, 32, 64);
            const int   oi = __shfl_xor(ii, 32, 64);
            ss = fmaxf(fmaxf(ss, os), fminf(bb, ob));
            const bool take = (ob > bb) || ((ob == bb) && (oi < ii));
            bb = fmaxf(bb, ob);
            ii = take ? oi : ii;
        }
        // pair swap: even col (plus branch) receives odd col (minus branch)
        const float bbO   = __shfl_xor(bb, 1, 64);
        const float ssO   = __shfl_xor(ss, 1, 64);
        const int   iiO   = __shfl_xor(ii, 1, 64);
        const int   mintO = __shfl_xor(mint, 1, 64);

        const bool doEpi = (h == 0) && (branch == 0) && (irow < N);
        bool close = false;
        if (doEpi) {
            const int qP = ii, qM = iiO;
            const float* gp_ = grid_part + (size_t)qP * 8;
            const float* gm_ = grid_part + (size_t)qM * 8;
            float vp[8], vm[8];
            float ep2 = 0.0f, em2 = 0.0f;
            bool coin = true;
#pragma unroll
            for (int j = 0; j < 8; ++j) {
                const float maskp = ((mint  >> (7 - j)) & 1) ? -1.0f : 1.0f;
                const float maskm = ((mintO >> (7 - j)) & 1) ? -1.0f : 1.0f;
                vp[j] = gp_[j] * maskp;
                vm[j] = gm_[j] * maskm;
                coin = coin && ((vp[j] - 0.25f) == (vm[j] + 0.25f));  // exact fp32
                const float dpj = (x[j] + 0.25f) - vp[j];
                const float dmj = (x[j] - 0.25f) - vm[j];
                ep2 = fmaf(dpj, dpj, ep2);
                em2 = fmaf(dmj, dmj, em2);
            }
            close = ((bb - ss) < SCORE_MARGIN) | ((bbO - ssO) < SCORE_MARGIN) |
                    (!coin && (fabsf(ep2 - em2) < ERR_MARGIN));
            if (!close) {
                // Coincident -> fp64 ref has pe==me bit-exactly -> which=false.
                const bool which = coin ? false : (ep2 < em2);
                const int rowp = idx_map[mint];
                const int rowm = idx_map[mintO];
                const int pi = allcombo_idx[(size_t)rowp * G + qP];
                const int mi = allcombo_idx[(size_t)rowm * G + qM];
                const float idxval = which ? (float)pi : (float)(mi - 32768);
                float* vout = out + (size_t)irow * 8;
#pragma unroll
                for (int j = 0; j < 8; ++j)
                    vout[j] = which ? (vp[j] - 0.25f) : (vm[j] + 0.25f);
                out[(size_t)N * 8 + irow] = idxval;
            }
        }

        // ---- inline fp64 fixup for flagged rows (R2-verified arithmetic) ----
        unsigned long long mb = __ballot(doEpi && close);
        while (mb) {
            const int b = (int)__ffsll(mb) - 1;   // flagged lane: h=0, even col
            mb &= (mb - 1);
            const int liF = b >> 1;
            const int iF  = job * 16 + liF;
            float xf[8];
#pragma unroll
            for (int j = 0; j < 8; ++j) xf[j] = __shfl(x[j], b, 64);

            double yapF[8], yamF[8];
            int negp = 0, negm = 0;
#pragma unroll
            for (int j = 0; j < 8; ++j) {
                const double xd = (double)xf[j];
                const double ypd = xd + 0.25;
                const double ymd = xd - 0.25;
                if (ypd < 0.0) negp |= (1 << (7 - j));
                if (ymd < 0.0) negm |= (1 << (7 - j));
                yapF[j] = fabs(ypd);
                yamF[j] = fabs(ymd);
            }
            int mintpF = negp, mintmF = negm;
            if (__popc(negp) & 1) { yapF[0] = -yapF[0]; mintpF ^= 128; }
            if (__popc(negm) & 1) { yamF[0] = -yamF[0]; mintmF ^= 128; }

            double bestpF = -1e300, bestmF = -1e300;
            int qpF = 0x7fffffff, qmF = 0x7fffffff;
            for (int j = lane; j < G; j += 64) {
                const float4 g0 = *(const float4*)(grid_part + (size_t)j * 8);
                const float4 g1 = *(const float4*)(grid_part + (size_t)j * 8 + 4);
                const double n = (double)grid_part_norm[j];
                const double t0 = (double)g0.x, t1 = (double)g0.y,
                             t2 = (double)g0.z, t3 = (double)g0.w,
                             t4 = (double)g1.x, t5 = (double)g1.y,
                             t6 = (double)g1.z, t7 = (double)g1.w;
                double dp, dm;
                dp = yapF[0] * t0;           dm = yamF[0] * t0;
                dp = fma(yapF[1], t1, dp);   dm = fma(yamF[1], t1, dm);
                dp = fma(yapF[2], t2, dp);   dm = fma(yamF[2], t2, dm);
                dp = fma(yapF[3], t3, dp);   dm = fma(yamF[3], t3, dm);
                dp = fma(yapF[4], t4, dp);   dm = fma(yamF[4], t4, dm);
                dp = fma(yapF[5], t5, dp);   dm = fma(yamF[5], t5, dm);
                dp = fma(yapF[6], t6, dp);   dm = fma(yamF[6], t6, dm);
                dp = fma(yapF[7], t7, dp);   dm = fma(yamF[7], t7, dm);
                const double sp = 2.0 * dp - n;
                const double sm = 2.0 * dm - n;
                if (sp > bestpF) { bestpF = sp; qpF = j; }
                if (sm > bestmF) { bestmF = sm; qmF = j; }
            }
#pragma unroll
            for (int off = 32; off > 0; off >>= 1) {
                double ob = __shfl_xor(bestpF, off, 64);
                int    oq = __shfl_xor(qpF, off, 64);
                if (ob > bestpF || (ob == bestpF && oq < qpF)) { bestpF = ob; qpF = oq; }
                ob = __shfl_xor(bestmF, off, 64);
                oq = __shfl_xor(qmF, off, 64);
                if (ob > bestmF || (ob == bestmF && oq < qmF)) { bestmF = ob; qmF = oq; }
            }
            if (lane == 0) {
                const float* gp_ = grid_part + (size_t)qpF * 8;
                const float* gm_ = grid_part + (size_t)qmF * 8;
                double vp[8], vm[8];
                double ep2 = 0.0, em2 = 0.0;
#pragma unroll
                for (int j = 0; j < 8; ++j) {
                    const double maskp = ((mintpF >> (7 - j)) & 1) ? -1.0 : 1.0;
                    const double maskm = ((mintmF >> (7 - j)) & 1) ? -1.0 : 1.0;
                    vp[j] = (double)gp_[j] * maskp;
                    vm[j] = (double)gm_[j] * maskm;
                    const double xd = (double)xf[j];
                    const double dpj = (xd + 0.25) - vp[j];
                    const double dmj = (xd - 0.25) - vm[j];
                    ep2 += dpj * dpj;
                    em2 += dmj * dmj;
                }
                const double ep = sqrt(ep2), em = sqrt(em2);
                const bool which = ep < em;
                const int rowp = idx_map[mintpF];
                const int rowm = idx_map[mintmF];
                const int pi = allcombo_idx[(size_t)rowp * G + qpF];
                const int mi = allcombo_idx[(size_t)rowm * G + qmF];
                const float idxval = which ? (float)pi : (float)(mi - 32768);
                float* vout = out + (size_t)iF * 8;
#pragma unroll
                for (int j = 0; j < 8; ++j) {
                    const double v = which ? (vp[j] - 0.25) : (vm[j] + 0.25);
                    vout[j] = (float)v;
                }
                out[(size_t)N * 8 + iF] = idxval;
            }
        }
    }
}

extern "C" void kernel_launch(void* const* d_in, const int* in_sizes, int n_in,
                              void* d_out, int out_size, void* d_ws, size_t ws_size,
                              hipStream_t stream) {
    const float* X    = (const float*)d_in[0];
    const float* gp   = (const float*)d_in[1];
    const float* gn   = (const float*)d_in[2];
    const int*   aci  = (const int*)d_in[3];
    const int*   imap = (const int*)d_in[4];
    // d_in[5] (int_map) and d_in[6] (grid_idx_map) are folded analytically.

    const int N = in_sizes[0] / 8;
    const int G = in_sizes[1] / 8;
    const int T = (G + 31) / 32;                 // tiles of 32 codewords
    const int nJobs = (N + 15) / 16;             // 16 rows per wave-job
    const int blocks = 512;                      // 2 blocks/CU, all resident
    const int jobStride = blocks * (TPB / 64);   // waves in grid
    const size_t shmem = (size_t)T * 512 + (size_t)T * 64;  // ~24.8KB

    hipLaunchKernelGGL(e8p_fused, dim3(blocks), dim3(TPB), shmem, stream,
                       X, gp, gn, aci, imap, (float*)d_out, N, G, T,
                       nJobs, jobStride);
}

// Round 11
// 138.491 us; speedup vs baseline: 1.3183x; 1.3183x over previous
//
#include <hip/hip_runtime.h>
#include <hip/hip_bf16.h>

typedef __attribute__((ext_vector_type(8)))  short bf16x8;
typedef __attribute__((ext_vector_type(16))) float f32x16;

#define TPB 256
// MFMA score error ~1e-4; VALU recompute error ~4e-5; 1e-3 margin >> sum.
#define SCORE_MARGIN 1e-3f
#define ERR_MARGIN   1e-3f

static __device__ __forceinline__ unsigned short bf16_rne(float v) {
    union { __hip_bfloat16 h; unsigned short u; } cv;
    cv.h = __float2bfloat16(v);
    return cv.u;
}
static __device__ __forceinline__ float bfhi(unsigned u) { return __uint_as_float(u << 16); }
static __device__ __forceinline__ float bflo(unsigned u) { return __uint_as_float(u & 0xffff0000u); }

// ---------------------------------------------------------------------------
// mfma_f32_32x32x16_bf16 (A=codewords, B=ya hi/lo, C=-n/2; verified since R8).
// R11: GROUP TRACKING — the 16 C-regs are 4 groups of 4 contiguous codewords
// (rows 8g+4h..+3). Track best/sec/tile on 4 group slots (12 regs vs R9's 48,
// which provably spilled: R10 WRITE_SIZE 22MB). Winner group's 4 scores are
// recomputed exactly post-loop (fp32 VALU) for index + intra-group gap; every
// other within-margin candidate's group-max enters the sec stream, so all
// ambiguity still flags into the bit-exact fp64 fixup (absmax 0.0 since R3).
// Output d_out (float32): [final_vals (N*8) | final_idxs (N)].
// ---------------------------------------------------------------------------
__global__ __launch_bounds__(TPB, 4) void e8p_fused(
    const float* __restrict__ X,
    const float* __restrict__ grid_part,
    const float* __restrict__ grid_part_norm,
    const int*   __restrict__ allcombo_idx,
    const int*   __restrict__ idx_map,
    float* __restrict__ out,
    int N, int G, int T)
{
    extern __shared__ __align__(16) unsigned char smem[];
    const int T32 = T * 32;
    unsigned char* ldsG = smem;                       // T32 cw x 16B bf16x8
    unsigned short* ldsN = (unsigned short*)(smem + (size_t)T32 * 16);
    // ldsN: per tile 32 bf16 = [h=0: 16 slots r][h=1: 16 slots r], value -n/2

    const int tid = threadIdx.x;

    // ---- stage codebook: g as bf16x8 (exact); -n/2 bf16 permuted to C order
    for (int c = tid; c < T32; c += TPB) {
        uint4 gv; float nv;
        if (c < G) {
            const float4 g0 = *(const float4*)(grid_part + (size_t)c * 8);
            const float4 g1 = *(const float4*)(grid_part + (size_t)c * 8 + 4);
            gv.x = (unsigned)bf16_rne(g0.x) | ((unsigned)bf16_rne(g0.y) << 16);
            gv.y = (unsigned)bf16_rne(g0.z) | ((unsigned)bf16_rne(g0.w) << 16);
            gv.z = (unsigned)bf16_rne(g1.x) | ((unsigned)bf16_rne(g1.y) << 16);
            gv.w = (unsigned)bf16_rne(g1.z) | ((unsigned)bf16_rne(g1.w) << 16);
            nv = -0.5f * grid_part_norm[c];           // in {-1..-6}: bf16-exact
        } else {
            gv.x = gv.y = gv.z = gv.w = 0u;  // pad cw: dot 0, C-slot -30000
            nv = -30000.0f;                  // bf16 ~ -29952: never wins/secs
        }
        *(uint4*)(ldsG + (size_t)c * 16) = gv;
        // C/D row w = (r&3) + 8*(r>>2) + 4h -> h=(w>>2)&1, r=(w&3)+4*(w>>3)
        const int t = c >> 5, w = c & 31;
        const int hh = (w >> 2) & 1;
        const int rr = (w & 3) + 4 * (w >> 3);
        ldsN[t * 32 + hh * 16 + rr] = bf16_rne(nv);
    }
    __syncthreads();

    const int lane = tid & 63;
    const int h    = lane >> 5;        // k-half / C-row offset 4h
    const int col  = lane & 31;        // B col = (input row, branch)
    const int wave = blockIdx.x * (TPB / 64) + (tid >> 6);

    const int li     = col >> 1;
    const int branch = col & 1;        // 0: +0.25, 1: -0.25
    const int irow   = wave * 16 + li;
    const int iload  = (irow < N) ? irow : 0;

    float x[8];
    {
        const float4 a = *(const float4*)(X + (size_t)iload * 8);
        const float4 b = *(const float4*)(X + (size_t)iload * 8 + 4);
        x[0]=a.x; x[1]=a.y; x[2]=a.z; x[3]=a.w;
        x[4]=b.x; x[5]=b.y; x[6]=b.z; x[7]=b.w;
    }

    // Branch prep (fp32 signs == fp64 signs)
    float ya[8]; int neg = 0;
    const float sh = branch ? -0.25f : 0.25f;
#pragma unroll
    for (int j = 0; j < 8; ++j) {
        const float yj = x[j] + sh;
        if (yj < 0.0f) neg |= (1 << (7 - j));
        ya[j] = fabsf(yj);
    }
    int mint = neg;
    if (__popc(neg) & 1) { ya[0] = -ya[0]; mint ^= 128; }

    // B fragment: h=0 -> bf16_hi(ya), h=1 -> bf16_lo residual
    bf16x8 bfrag;
#pragma unroll
    for (int j = 0; j < 8; ++j) {
        const unsigned short hi = bf16_rne(ya[j]);
        const unsigned short lo = bf16_rne(ya[j] - bfhi((unsigned)hi));
        bfrag[j] = (short)(h ? lo : hi);
    }

    float best[4], sec[4]; int qt[4];
#pragma unroll
    for (int g = 0; g < 4; ++g) { best[g] = -1e30f; sec[g] = -1e30f; qt[g] = 0; }

    const unsigned aoff = (unsigned)col * 16u;
    const unsigned char* nbase = (const unsigned char*)ldsN + h * 32;

    bf16x8 afragN = *(const bf16x8*)(ldsG + aoff);
    uint4 n0N = *(const uint4*)(nbase);
    uint4 n1N = *(const uint4*)(nbase + 16);

    for (int t = 0; t < T; ++t) {
        const bf16x8 afrag = afragN;
        const uint4 n0 = n0N, n1 = n1N;
        const int tn = (t + 1 < T) ? (t + 1) : t;
        afragN = *(const bf16x8*)(ldsG + (size_t)tn * 512 + aoff);
        n0N = *(const uint4*)(nbase + (size_t)tn * 64);
        n1N = *(const uint4*)(nbase + (size_t)tn * 64 + 16);

        f32x16 acc;
        acc[0]=bfhi(n0.x);  acc[1]=bflo(n0.x);  acc[2]=bfhi(n0.y);  acc[3]=bflo(n0.y);
        acc[4]=bfhi(n0.z);  acc[5]=bflo(n0.z);  acc[6]=bfhi(n0.w);  acc[7]=bflo(n0.w);
        acc[8]=bfhi(n1.x);  acc[9]=bflo(n1.x);  acc[10]=bfhi(n1.y); acc[11]=bflo(n1.y);
        acc[12]=bfhi(n1.z); acc[13]=bflo(n1.z); acc[14]=bfhi(n1.w); acc[15]=bflo(n1.w);
        acc = __builtin_amdgcn_mfma_f32_32x32x16_bf16(afrag, bfrag, acc, 0, 0, 0);

#pragma unroll
        for (int g = 0; g < 4; ++g) {
            const float m = fmaxf(fmaxf(acc[4*g], acc[4*g+1]),
                                  fmaxf(acc[4*g+2], acc[4*g+3]));
            const bool gt = m > best[g];
            sec[g]  = __builtin_amdgcn_fmed3f(m, best[g], sec[g]);
            best[g] = fmaxf(best[g], m);
            qt[g]   = gt ? t : qt[g];
        }
    }

    // ---- reduce 4 group slots -> 1 (lexicographic; exact ties flag via ss)
    float bb = best[0], ss = sec[0];
    int   ib = (qt[0] << 5) + 4 * h;                  // base(g=0) = 4h
#pragma unroll
    for (int g = 1; g < 4; ++g) {
        const int ibg = (qt[g] << 5) + 8 * g + 4 * h;
        const float br = best[g];
        ss = fmaxf(fmaxf(ss, sec[g]), fminf(bb, br));
        const bool take = (br > bb) || ((br == bb) && (ibg < ib));
        bb = fmaxf(bb, br);
        ib = take ? ibg : ib;
    }
    {   // butterfly across the two k-half lane groups (offset 32)
        const float ob = __shfl_xor(bb, 32, 64);
        const float os = __shfl_xor(ss, 32, 64);
        const int   oi = __shfl_xor(ib, 32, 64);
        ss = fmaxf(fmaxf(ss, os), fminf(bb, ob));
        const bool take = (ob > bb) || ((ob == bb) && (oi < ib));
        bb = fmaxf(bb, ob);
        ib = take ? oi : ib;
    }

    // ---- exact recompute of the winning group's 4 scores (all 64 lanes:
    // lane c and c+32 hold identical (bb,ss,ib) and the same ya, no divergence)
    float hiF[8], loF[8];
#pragma unroll
    for (int j = 0; j < 8; ++j) {
        hiF[j] = bfhi((unsigned)bf16_rne(ya[j]));
        loF[j] = ya[j] - hiF[j];
    }
    const int tW   = ib >> 5;
    const int base = ib & 31;
    float sm = -1e30f, sec4 = -1e30f; int km = 0;
#pragma unroll
    for (int k = 0; k < 4; ++k) {
        const int w  = base + k;
        const uint4 gv = *(const uint4*)(ldsG + ((size_t)tW * 32 + w) * 16);
        const int hn = (w >> 2) & 1;
        const int rn = (w & 3) + 4 * (w >> 3);
        const float nv = bfhi((unsigned)ldsN[tW * 32 + hn * 16 + rn]);
        float g0 = bfhi(gv.x), g1 = bflo(gv.x), g2 = bfhi(gv.y), g3 = bflo(gv.y);
        float g4 = bfhi(gv.z), g5 = bflo(gv.z), g6 = bfhi(gv.w), g7 = bflo(gv.w);
        float s = nv;
        s = fmaf(hiF[0], g0, s); s = fmaf(hiF[1], g1, s);
        s = fmaf(hiF[2], g2, s); s = fmaf(hiF[3], g3, s);
        s = fmaf(hiF[4], g4, s); s = fmaf(hiF[5], g5, s);
        s = fmaf(hiF[6], g6, s); s = fmaf(hiF[7], g7, s);
        s = fmaf(loF[0], g0, s); s = fmaf(loF[1], g1, s);
        s = fmaf(loF[2], g2, s); s = fmaf(loF[3], g3, s);
        s = fmaf(loF[4], g4, s); s = fmaf(loF[5], g5, s);
        s = fmaf(loF[6], g6, s); s = fmaf(loF[7], g7, s);
        const bool gt = s > sm;                        // first-max-wins
        sec4 = __builtin_amdgcn_fmed3f(s, sm, sec4);
        sm   = fmaxf(sm, s);
        km   = gt ? k : km;
    }
    const int  qfin   = tW * 32 + base + km;
    const int  closeB = ((sm - sec4) < SCORE_MARGIN) | ((bb - ss) < SCORE_MARGIN);

    // pair swap: even col (plus branch) receives odd col (minus branch)
    const int qO     = __shfl_xor(qfin, 1, 64);
    const int closeO = __shfl_xor(closeB, 1, 64);
    const int mintO  = __shfl_xor(mint, 1, 64);

    const bool doEpi = (h == 0) && (branch == 0) && (irow < N);
    bool close = false;
    if (doEpi) {
        const int qP = qfin, qM = qO;
        const float* gp_ = grid_part + (size_t)qP * 8;
        const float* gm_ = grid_part + (size_t)qM * 8;
        float vp[8], vm[8];
        float ep2 = 0.0f, em2 = 0.0f;
        bool coin = true;
#pragma unroll
        for (int j = 0; j < 8; ++j) {
            const float maskp = ((mint  >> (7 - j)) & 1) ? -1.0f : 1.0f;
            const float maskm = ((mintO >> (7 - j)) & 1) ? -1.0f : 1.0f;
            vp[j] = gp_[j] * maskp;
            vm[j] = gm_[j] * maskm;
            coin = coin && ((vp[j] - 0.25f) == (vm[j] + 0.25f));  // exact fp32
            const float dpj = (x[j] + 0.25f) - vp[j];
            const float dmj = (x[j] - 0.25f) - vm[j];
            ep2 = fmaf(dpj, dpj, ep2);
            em2 = fmaf(dmj, dmj, em2);
        }
        close = closeB | closeO | (!coin && (fabsf(ep2 - em2) < ERR_MARGIN));
        if (!close) {
            // Coincident -> fp64 ref has pe==me bit-exactly -> which=false.
            const bool which = coin ? false : (ep2 < em2);
            const int rowp = idx_map[mint];
            const int rowm = idx_map[mintO];
            const int pi = allcombo_idx[(size_t)rowp * G + qP];
            const int mi = allcombo_idx[(size_t)rowm * G + qM];
            const float idxval = which ? (float)pi : (float)(mi - 32768);
            float* vout = out + (size_t)irow * 8;
#pragma unroll
            for (int j = 0; j < 8; ++j)
                vout[j] = which ? (vp[j] - 0.25f) : (vm[j] + 0.25f);
            out[(size_t)N * 8 + irow] = idxval;
        }
    }

    // ---- inline fp64 fixup for flagged rows (R2-verified arithmetic) ----
    unsigned long long mb = __ballot(doEpi && close);
    while (mb) {
        const int b = (int)__ffsll(mb) - 1;   // flagged lane: h=0, even col
        mb &= (mb - 1);
        const int liF = b >> 1;
        const int iF  = wave * 16 + liF;
        float xf[8];
#pragma unroll
        for (int j = 0; j < 8; ++j) xf[j] = __shfl(x[j], b, 64);

        double yapF[8], yamF[8];
        int negp = 0, negm = 0;
#pragma unroll
        for (int j = 0; j < 8; ++j) {
            const double xd = (double)xf[j];
            const double ypd = xd + 0.25;
            const double ymd = xd - 0.25;
            if (ypd < 0.0) negp |= (1 << (7 - j));
            if (ymd < 0.0) negm |= (1 << (7 - j));
            yapF[j] = fabs(ypd);
            yamF[j] = fabs(ymd);
        }
        int mintpF = negp, mintmF = negm;
        if (__popc(negp) & 1) { yapF[0] = -yapF[0]; mintpF ^= 128; }
        if (__popc(negm) & 1) { yamF[0] = -yamF[0]; mintmF ^= 128; }

        double bestpF = -1e300, bestmF = -1e300;
        int qpF = 0x7fffffff, qmF = 0x7fffffff;
        for (int j = lane; j < G; j += 64) {
            const float4 g0 = *(const float4*)(grid_part + (size_t)j * 8);
            const float4 g1 = *(const float4*)(grid_part + (size_t)j * 8 + 4);
            const double n = (double)grid_part_norm[j];
            const double t0 = (double)g0.x, t1 = (double)g0.y,
                         t2 = (double)g0.z, t3 = (double)g0.w,
                         t4 = (double)g1.x, t5 = (double)g1.y,
                         t6 = (double)g1.z, t7 = (double)g1.w;
            double dp, dm;
            dp = yapF[0] * t0;           dm = yamF[0] * t0;
            dp = fma(yapF[1], t1, dp);   dm = fma(yamF[1], t1, dm);
            dp = fma(yapF[2], t2, dp);   dm = fma(yamF[2], t2, dm);
            dp = fma(yapF[3], t3, dp);   dm = fma(yamF[3], t3, dm);
            dp = fma(yapF[4], t4, dp);   dm = fma(yamF[4], t4, dm);
            dp = fma(yapF[5], t5, dp);   dm = fma(yamF[5], t5, dm);
            dp = fma(yapF[6], t6, dp);   dm = fma(yamF[6], t6, dm);
            dp = fma(yapF[7], t7, dp);   dm = fma(yamF[7], t7, dm);
            const double sp = 2.0 * dp - n;
            const double sm2 = 2.0 * dm - n;
            if (sp > bestpF) { bestpF = sp; qpF = j; }
            if (sm2 > bestmF) { bestmF = sm2; qmF = j; }
        }
#pragma unroll
        for (int off = 32; off > 0; off >>= 1) {
            double ob = __shfl_xor(bestpF, off, 64);
            int    oq = __shfl_xor(qpF, off, 64);
            if (ob > bestpF || (ob == bestpF && oq < qpF)) { bestpF = ob; qpF = oq; }
            ob = __shfl_xor(bestmF, off, 64);
            oq = __shfl_xor(qmF, off, 64);
            if (ob > bestmF || (ob == bestmF && oq < qmF)) { bestmF = ob; qmF = oq; }
        }
        if (lane == 0) {
            const float* gp_ = grid_part + (size_t)qpF * 8;
            const float* gm_ = grid_part + (size_t)qmF * 8;
            double vp[8], vm[8];
            double ep2 = 0.0, em2 = 0.0;
#pragma unroll
            for (int j = 0; j < 8; ++j) {
                const double maskp = ((mintpF >> (7 - j)) & 1) ? -1.0 : 1.0;
                const double maskm = ((mintmF >> (7 - j)) & 1) ? -1.0 : 1.0;
                vp[j] = (double)gp_[j] * maskp;
                vm[j] = (double)gm_[j] * maskm;
                const double xd = (double)xf[j];
                const double dpj = (xd + 0.25) - vp[j];
                const double dmj = (xd - 0.25) - vm[j];
                ep2 += dpj * dpj;
                em2 += dmj * dmj;
            }
            const double ep = sqrt(ep2), em = sqrt(em2);
            const bool which = ep < em;
            const int rowp = idx_map[mintpF];
            const int rowm = idx_map[mintmF];
            const int pi = allcombo_idx[(size_t)rowp * G + qpF];
            const int mi = allcombo_idx[(size_t)rowm * G + qmF];
            const float idxval = which ? (float)pi : (float)(mi - 32768);
            float* vout = out + (size_t)iF * 8;
#pragma unroll
            for (int j = 0; j < 8; ++j) {
                const double v = which ? (vp[j] - 0.25) : (vm[j] + 0.25);
                vout[j] = (float)v;
            }
            out[(size_t)N * 8 + iF] = idxval;
        }
    }
}

extern "C" void kernel_launch(void* const* d_in, const int* in_sizes, int n_in,
                              void* d_out, int out_size, void* d_ws, size_t ws_size,
                              hipStream_t stream) {
    const float* X    = (const float*)d_in[0];
    const float* gp   = (const float*)d_in[1];
    const float* gn   = (const float*)d_in[2];
    const int*   aci  = (const int*)d_in[3];
    const int*   imap = (const int*)d_in[4];
    // d_in[5] (int_map) and d_in[6] (grid_idx_map) are folded analytically.

    const int N = in_sizes[0] / 8;
    const int G = in_sizes[1] / 8;
    const int T = (G + 31) / 32;                 // tiles of 32 codewords
    const int blocks = (N + 63) / 64;            // 4 waves x 16 rows per block
    const size_t shmem = (size_t)T * 512 + (size_t)T * 64;  // ~24.8KB

    hipLaunchKernelGGL(e8p_fused, dim3(blocks), dim3(TPB), shmem, stream,
                       X, gp, gn, aci, imap, (float*)d_out, N, G, T);
}